// Round 5
// baseline (2104.124 us; speedup 1.0000x reference)
//
#include <hip/hip_runtime.h>
#include <hip/hip_bf16.h>
#include <math.h>

#define N_NODES 100000
#define N_EDGES 1600000
#define NFEAT 256
#define NHID1 128
#define NCLASS 64
#define NUM_GRAPHS 64

// bucket geometry: bucket = col >> 6 (64 nodes per bucket)
#define BSHIFT 6
#define BNODES 64
#define NBUCK2 1563                  // ceil(100000/64)
#define NBPAD 2048                   // padded for scan
#define EPB 8192                     // edges per block in binning passes
#define NBLK_A 196                   // ceil(1600000/8192)

typedef __attribute__((ext_vector_type(8))) short bf16x8;
typedef __attribute__((ext_vector_type(4))) float f32x4;

// ---------------- bf16 helpers (bit-level, RNE) ----------------

__device__ __forceinline__ unsigned short f2bf(float f) {
    unsigned u = __float_as_uint(f);
    u += 0x7fffu + ((u >> 16) & 1u);   // round to nearest even
    return (unsigned short)(u >> 16);
}
__device__ __forceinline__ unsigned packbf2(float lo, float hi) {
    return (unsigned)f2bf(lo) | ((unsigned)f2bf(hi) << 16);
}
__device__ __forceinline__ float bflo(unsigned p) { return __uint_as_float(p << 16); }
__device__ __forceinline__ float bfhi(unsigned p) { return __uint_as_float(p & 0xffff0000u); }

// ---------------- pass P1: bucket histogram + per-edge rank persist ----------------
// rk[idx] = rank of edge idx within (block, bucket); hbk[b][k] = block b count in bucket k

__global__ __launch_bounds__(256) void hist_rank_kernel(const int* __restrict__ cols,
                                                        int* __restrict__ ghist,
                                                        unsigned short* __restrict__ rk,
                                                        int* __restrict__ hbk, int nE) {
    __shared__ int h[NBUCK2];
    const int tid = threadIdx.x;
    for (int i = tid; i < NBUCK2; i += 256) h[i] = 0;
    __syncthreads();
    long base = (long)blockIdx.x * EPB;
    for (int j = tid; j < EPB; j += 256) {
        long idx = base + j;
        if (idx < nE) rk[idx] = (unsigned short)atomicAdd(&h[cols[idx] >> BSHIFT], 1);
    }
    __syncthreads();
    int* hrow = hbk + blockIdx.x * NBUCK2;
    for (int i = tid; i < NBUCK2; i += 256) {
        int v = h[i];
        hrow[i] = v;
        if (v) atomicAdd(&ghist[i], v);
    }
}

// ---------------- pass P2: bucket scan over padded 2048 (512 thr x 4 elems) ----------------

__global__ __launch_bounds__(512) void bucket_scan_kernel(const int* __restrict__ ghist,
                                                          int* __restrict__ gbase,
                                                          int* __restrict__ gcursor) {
    __shared__ int ps[512];
    int t = threadIdx.x;
    int b4 = t * 4;
    int v0 = ghist[b4], v1 = ghist[b4 + 1], v2 = ghist[b4 + 2], v3 = ghist[b4 + 3];
    int s = v0 + v1 + v2 + v3;
    ps[t] = s;
    __syncthreads();
    for (int off = 1; off < 512; off <<= 1) {
        int add = (t >= off) ? ps[t - off] : 0;
        __syncthreads();
        ps[t] += add;
        __syncthreads();
    }
    int excl = ps[t] - s;
    if (b4 < NBUCK2)     { gbase[b4] = excl;     gcursor[b4] = excl; }
    excl += v0;
    if (b4 + 1 < NBUCK2) { gbase[b4 + 1] = excl; gcursor[b4 + 1] = excl; }
    excl += v1;
    if (b4 + 2 < NBUCK2) { gbase[b4 + 2] = excl; gcursor[b4 + 2] = excl; }
    excl += v2;
    if (b4 + 3 < NBUCK2) { gbase[b4 + 3] = excl; gcursor[b4 + 3] = excl; }
}

// ---------------- pass P3: scatter edges into bucket-grouped csc_tmp ----------------
// record: .x = row | ((col&63)<<17), .y = w bits

__global__ __launch_bounds__(256) void scatter_bucket_kernel(const int* __restrict__ rows,
                                                             const int* __restrict__ cols,
                                                             const float* __restrict__ w,
                                                             int* __restrict__ gcursor,
                                                             const int* __restrict__ hbk,
                                                             const unsigned short* __restrict__ rk,
                                                             int2* __restrict__ csc_tmp, int nE) {
    __shared__ int bb[NBUCK2];
    const int tid = threadIdx.x;
    const int* hrow = hbk + blockIdx.x * NBUCK2;
    for (int i = tid; i < NBUCK2; i += 256) {
        int v = hrow[i];
        bb[i] = v ? atomicAdd(&gcursor[i], v) : 0;
    }
    __syncthreads();
    long base = (long)blockIdx.x * EPB;
    for (int j = tid; j < EPB; j += 256) {
        long idx = base + j;
        if (idx < nE) {
            int c = cols[idx];
            int b = c >> BSHIFT;
            int pos = bb[b] + (int)rk[idx];
            csc_tmp[pos] = make_int2((rows[idx] & 0x1FFFF) | ((c & 63) << 17),
                                     __float_as_int(w[idx]));
        }
    }
}

// ---------------- pass P4: per-bucket weight sums -> dinv ----------------

__global__ __launch_bounds__(256) void dinv_kernel(const int2* __restrict__ csc_tmp,
                                                   const int* __restrict__ gbase,
                                                   const int* __restrict__ ghist,
                                                   float* __restrict__ dinv, int n) {
    __shared__ float wsum[BNODES];
    const int tid = threadIdx.x;
    const int b = blockIdx.x;
    if (tid < BNODES) wsum[tid] = 0.f;
    __syncthreads();
    int s = gbase[b], e = s + ghist[b];
    for (int i = s + tid; i < e; i += 256) {
        int2 rec = csc_tmp[i];
        atomicAdd(&wsum[((unsigned)rec.x) >> 17], __int_as_float(rec.y));
    }
    __syncthreads();
    if (tid < BNODES) {
        int gn = (b << BSHIFT) + tid;
        if (gn < n) dinv[gn] = rsqrtf(1.0f + wsum[tid]);
    }
}

// ---------------- weight transpose + bf16 pack: W[K][Nn] f32 -> WT[Nn][K/2] dwords ----------------

__global__ void transpose_bf_kernel(const float* __restrict__ W, unsigned* __restrict__ WT,
                                    int K, int Nn) {
    int idx = blockIdx.x * blockDim.x + threadIdx.x;
    int total = Nn * (K / 2);
    if (idx < total) {
        int n = idx / (K / 2);
        int kp = idx - n * (K / 2);
        WT[idx] = packbf2(W[(2 * kp) * Nn + n], W[(2 * kp + 1) * Nn + n]);
    }
}

// ---------------- MFMA bf16 GEMM: C[M,NT] = A[M,KK] @ BT^T, epilogue *rowscale -> bf16 ----------------

template <int NT, int KK, bool ABF16>
__global__ __launch_bounds__(256) void gemm_mfma(const void* __restrict__ Av,
                                                 const unsigned* __restrict__ BT,
                                                 const float* __restrict__ rowscale,
                                                 unsigned short* __restrict__ C,
                                                 int M) {
    constexpr int CT = NT / 16;
    constexpr int KD = KK / 2;          // dwords per bf16 row
    __shared__ unsigned Al[4][128][4];
    __shared__ unsigned Bl[4][NT][4];
    const int tid = threadIdx.x;
    const int wave = tid >> 6;
    const int lane = tid & 63;
    const int quad = lane >> 4;
    const int l16 = lane & 15;
    const int row0 = blockIdx.x * 128;

    f32x4 acc[2][CT] = {};

    for (int k0 = 0; k0 < KK; k0 += 32) {
        // ---- stage A ----
        if (ABF16) {
            const unsigned* Ab = (const unsigned*)Av;
            #pragma unroll
            for (int i = 0; i < 2; i++) {
                int idx = tid + i * 256;
                int ar = idx >> 2, aq = idx & 3;
                uint4 v = make_uint4(0, 0, 0, 0);
                if (row0 + ar < M)
                    v = *(const uint4*)(Ab + (long)(row0 + ar) * KD + k0 / 2 + aq * 4);
                *(uint4*)&Al[aq][ar][0] = v;
            }
        } else {
            const float* Af = (const float*)Av;
            int ar = tid >> 1, ah = tid & 1;
            float4 v0 = make_float4(0, 0, 0, 0), v1 = v0, v2 = v0, v3 = v0;
            if (row0 + ar < M) {
                const float* p = Af + (long)(row0 + ar) * KK + k0 + ah * 16;
                v0 = *(const float4*)p;
                v1 = *(const float4*)(p + 4);
                v2 = *(const float4*)(p + 8);
                v3 = *(const float4*)(p + 12);
            }
            uint4 d0 = make_uint4(packbf2(v0.x, v0.y), packbf2(v0.z, v0.w),
                                  packbf2(v1.x, v1.y), packbf2(v1.z, v1.w));
            uint4 d1 = make_uint4(packbf2(v2.x, v2.y), packbf2(v2.z, v2.w),
                                  packbf2(v3.x, v3.y), packbf2(v3.z, v3.w));
            *(uint4*)&Al[ah * 2 + 0][ar][0] = d0;
            *(uint4*)&Al[ah * 2 + 1][ar][0] = d1;
        }
        // ---- stage B ----
        #pragma unroll
        for (int i = 0; i < NT / 64; i++) {
            int idx = tid + i * 256;
            int br = idx >> 2, bq = idx & 3;
            *(uint4*)&Bl[bq][br][0] = *(const uint4*)(BT + (long)br * KD + k0 / 2 + bq * 4);
        }
        __syncthreads();

        bf16x8 af[2];
        #pragma unroll
        for (int rt = 0; rt < 2; rt++)
            af[rt] = *(const bf16x8*)&Al[quad][wave * 32 + rt * 16 + l16][0];
        #pragma unroll
        for (int ct = 0; ct < CT; ct++) {
            bf16x8 bfr = *(const bf16x8*)&Bl[quad][ct * 16 + l16][0];
            acc[0][ct] = __builtin_amdgcn_mfma_f32_16x16x32_bf16(af[0], bfr, acc[0][ct], 0, 0, 0);
            acc[1][ct] = __builtin_amdgcn_mfma_f32_16x16x32_bf16(af[1], bfr, acc[1][ct], 0, 0, 0);
        }
        __syncthreads();
    }

    // epilogue: C/D layout col=lane&15, row=quad*4+reg
    #pragma unroll
    for (int rt = 0; rt < 2; rt++) {
        #pragma unroll
        for (int reg = 0; reg < 4; reg++) {
            int row = row0 + wave * 32 + rt * 16 + quad * 4 + reg;
            if (row < M) {
                float sc = rowscale[row];
                unsigned short* cp = C + (long)row * NT + l16;
                #pragma unroll
                for (int ct = 0; ct < CT; ct++)
                    cp[ct * 16] = f2bf(acc[rt][ct][reg] * sc);
            }
        }
    }
}

// ---------------- bucket-gather: edge-parallel aggregate into LDS node tile ----------------
// One block per 64-node bucket. Edges consumed sequentially from csc_tmp (coalesced
// record reads), source rows gathered exactly as before, accumulation via ds_add_f32
// into acc[64][F] (+4 pad). No per-node loops -> no degree divergence; no starts/cnt.
// OUTMODE: 1 = bf16 out, 2 = fused global-add-pool (f32 pooled output).

template <int F, int OUTMODE>
__global__ __launch_bounds__(256) void bucket_gather(const unsigned* __restrict__ xsb,
                                                     const int2* __restrict__ csc_tmp,
                                                     const int* __restrict__ gbase,
                                                     const int* __restrict__ ghist,
                                                     const float* __restrict__ dinv,
                                                     const float* __restrict__ bias,
                                                     const int* __restrict__ batch,
                                                     void* __restrict__ outv, int n) {
    constexpr int FU = F / 2;            // dwords per feature row
    constexpr int LPE = F / 8;           // lanes per edge (16B of bf16 per lane)
    constexpr int EPI = 256 / LPE;       // edges in flight per block iteration
    constexpr int ST = F + 4;            // LDS row stride (floats) - bank rotation
    __shared__ float acc[BNODES][ST];
    __shared__ float lp[4][64];
    const int tid = threadIdx.x;
    const int b = blockIdx.x;

    for (int i = tid; i < BNODES * ST; i += 256) ((float*)acc)[i] = 0.f;
    int g0 = 0;
    if (OUTMODE == 2) {
        lp[tid >> 6][tid & 63] = 0.f;
        g0 = batch[b << BSHIFT];
    }
    __syncthreads();

    const int s = gbase[b];
    const int e = s + ghist[b];
    const int slot = tid / LPE;
    const int lane = tid - slot * LPE;
    const unsigned* lb = xsb + lane * 4;

    // software-pipelined edge loop: next records load while current gathers are in flight
    int j = s + slot;
    bool have = (j < e);
    int2 rec = have ? csc_tmp[j] : make_int2(0, 0);
    while (have) {
        int row = rec.x & 0x1FFFF;
        int local = ((unsigned)rec.x) >> 17;
        float w = __int_as_float(rec.y);
        uint4 p = *(const uint4*)(lb + (long)row * FU);
        int jn = j + EPI;
        bool have2 = (jn < e);
        int2 rec2 = have2 ? csc_tmp[jn] : make_int2(0, 0);
        float* arow = &acc[local][lane * 8];
        atomicAdd(&arow[0], bflo(p.x) * w);
        atomicAdd(&arow[1], bfhi(p.x) * w);
        atomicAdd(&arow[2], bflo(p.y) * w);
        atomicAdd(&arow[3], bfhi(p.y) * w);
        atomicAdd(&arow[4], bflo(p.z) * w);
        atomicAdd(&arow[5], bfhi(p.z) * w);
        atomicAdd(&arow[6], bflo(p.w) * w);
        atomicAdd(&arow[7], bfhi(p.w) * w);
        j = jn; rec = rec2; have = have2;
    }
    __syncthreads();

    // finalize: out = relu(dinv * (acc + self) + bias); coalesced
    for (int idx = tid; idx < BNODES * FU; idx += 256) {
        int node = idx / FU;
        int dq = idx - node * FU;
        int gn = (b << BSHIFT) + node;
        if (gn >= n) continue;
        float d = dinv[gn];
        unsigned spv = xsb[(long)gn * FU + dq];
        float v0 = d * (acc[node][2 * dq] + bflo(spv)) + bias[2 * dq];
        float v1 = d * (acc[node][2 * dq + 1] + bfhi(spv)) + bias[2 * dq + 1];
        v0 = fmaxf(v0, 0.f);
        v1 = fmaxf(v1, 0.f);
        if (OUTMODE == 1) {
            ((unsigned*)outv)[(long)gn * FU + dq] = packbf2(v0, v1);
        } else {
            int g = batch[gn];
            int rel = g - g0;
            if (rel >= 0 && rel < 4) {
                atomicAdd(&lp[rel][2 * dq], v0);
                atomicAdd(&lp[rel][2 * dq + 1], v1);
            } else {
                float* pooled = (float*)outv;
                atomicAdd(&pooled[g * 64 + 2 * dq], v0);
                atomicAdd(&pooled[g * 64 + 2 * dq + 1], v1);
            }
        }
    }
    if (OUTMODE == 2) {
        __syncthreads();
        int rel = tid >> 6, f = tid & 63;
        float v = lp[rel][f];
        int g = g0 + rel;
        if (v != 0.f && g < NUM_GRAPHS)
            atomicAdd(&((float*)outv)[g * 64 + f], v);
    }
}

// ---------------- head: 256 threads, all-LDS MLP + log_softmax + argmax ----------------

__global__ __launch_bounds__(256) void head_kernel(const float* __restrict__ pooled,
                                                   const float* __restrict__ l1w,
                                                   const float* __restrict__ l1b,
                                                   const float* __restrict__ l2w,
                                                   const float* __restrict__ l2b,
                                                   float* __restrict__ out) {
    __shared__ float P[64][68];
    __shared__ float W[64][68];
    __shared__ float red0[64][4];
    __shared__ float red1[64][4];
    const int tid = threadIdx.x;

    for (int i = tid; i < 1024; i += 256) {
        int r = i >> 4;
        int cq = (i & 15) * 4;
        *(float4*)&P[r][cq] = *(const float4*)&pooled[r * 64 + cq];
        *(float4*)&W[r][cq] = *(const float4*)&l1w[r * 64 + cq];
    }
    __syncthreads();

    const int g = tid >> 2;
    const int q = tid & 3;
    const int j0 = q * 16;

    float hacc[16];
    #pragma unroll
    for (int jj = 0; jj < 16; jj++) hacc[jj] = l1b[j0 + jj];

    for (int c = 0; c < 64; c++) {
        float pv = P[g][c];
        #pragma unroll
        for (int jj = 0; jj < 16; jj += 4) {
            float4 wv = *(const float4*)&W[c][j0 + jj];
            hacc[jj + 0] += pv * wv.x;
            hacc[jj + 1] += pv * wv.y;
            hacc[jj + 2] += pv * wv.z;
            hacc[jj + 3] += pv * wv.w;
        }
    }

    float o0 = 0.f, o1 = 0.f;
    #pragma unroll
    for (int jj = 0; jj < 16; jj++) {
        float h = fmaxf(hacc[jj], 0.f);
        o0 += h * l2w[(j0 + jj) * 2];
        o1 += h * l2w[(j0 + jj) * 2 + 1];
    }
    red0[g][q] = o0;
    red1[g][q] = o1;
    __syncthreads();

    if (q == 0) {
        float a0 = red0[g][0] + red0[g][1] + red0[g][2] + red0[g][3] + l2b[0];
        float a1 = red1[g][0] + red1[g][1] + red1[g][2] + red1[g][3] + l2b[1];
        float m = fmaxf(a0, a1);
        float lse = m + logf(expf(a0 - m) + expf(a1 - m));
        out[g * 2 + 0] = a0 - lse;
        out[g * 2 + 1] = a1 - lse;
        out[128 + g] = (a1 > a0) ? 1.f : 0.f;
        out[192 + g * 2 + 0] = a0;
        out[192 + g * 2 + 1] = a1;
    }
}

// ---------------- launch ----------------

extern "C" void kernel_launch(void* const* d_in, const int* in_sizes, int n_in,
                              void* d_out, int out_size, void* d_ws, size_t ws_size,
                              hipStream_t stream) {
    const float* x   = (const float*)d_in[0];           // [N, 256]
    const int* eidx  = (const int*)d_in[1];             // [2, E] flat
    const float* ew  = (const float*)d_in[2];           // [E]
    const int* batch = (const int*)d_in[3];             // [N]
    const float* W1  = (const float*)d_in[4];           // [256,128]
    const float* b1  = (const float*)d_in[5];
    const float* W2  = (const float*)d_in[6];           // [128,64]
    const float* b2  = (const float*)d_in[7];
    const float* l1w = (const float*)d_in[8];           // [64,64]
    const float* l1b = (const float*)d_in[9];
    const float* l2w = (const float*)d_in[10];          // [64,2]
    const float* l2b = (const float*)d_in[11];
    float* out = (float*)d_out;

    const int N = N_NODES, E = N_EDGES;
    const int* rows = eidx;
    const int* cols = eidx + E;

    // workspace layout (float offsets; 16B alignment for vector arrays)
    float* ws = (float*)d_ws;
    int*   ghist   = (int*)ws;                  // NBPAD
    int*   gbase   = ghist + NBPAD;             // NBPAD
    int*   gcursor = gbase + NBPAD;             // NBPAD
    float* dinv    = (float*)(gcursor + NBPAD); // N
    unsigned* w1t  = (unsigned*)(dinv + N);     // 16384
    unsigned* w2t  = w1t + 16384;               // 4096
    int2*  csc_tmp = (int2*)(w2t + 4096);       // E int2 (16B-aligned)
    unsigned* xsb  = (unsigned*)(csc_tmp + E);  // N*64 dw
    unsigned* h1b  = xsb + (long)N * 64;        // N*64 dw
    float* pooled  = (float*)(h1b + (long)N * 64);  // 4096
    unsigned* hw2b = xsb;                       // reuse dead xsb: N*32 dw
    // transient aliases into h1b (dead until bucket_gather<128> writes it):
    unsigned short* rk = (unsigned short*)h1b;              // E u16 (3.2 MB)
    int* hbk = (int*)h1b + 800000;                          // NBLK_A*NBUCK2 ints (1.2 MB)

    // 1. bucket histogram + per-edge rank persist
    hipMemsetAsync(ghist, 0, NBPAD * sizeof(int), stream);
    hist_rank_kernel<<<NBLK_A, 256, 0, stream>>>(cols, ghist, rk, hbk, E);

    // 2. bucket scan -> gbase/gcursor
    bucket_scan_kernel<<<1, 512, 0, stream>>>(ghist, gbase, gcursor);

    // 3. scatter into bucket-grouped csc_tmp (rank reuse)
    scatter_bucket_kernel<<<NBLK_A, 256, 0, stream>>>(rows, cols, ew, gcursor, hbk, rk, csc_tmp, E);

    // 4. per-bucket weight sums -> dinv
    dinv_kernel<<<NBUCK2, 256, 0, stream>>>(csc_tmp, gbase, ghist, dinv, N);

    // 5. weight prep
    transpose_bf_kernel<<<64, 256, 0, stream>>>(W1, w1t, NFEAT, NHID1);
    transpose_bf_kernel<<<16, 256, 0, stream>>>(W2, w2t, NHID1, NCLASS);

    // 6. GEMM1 (MFMA): xsb = bf16((x @ W1) * dinv[row])
    gemm_mfma<NHID1, NFEAT, false><<<(N + 127) / 128, 256, 0, stream>>>(
        x, w1t, dinv, (unsigned short*)xsb, N);

    // 7. gather layer 1 (edge-parallel, LDS accum): h1b = bf16(relu(dinv*(agg+self)+b1))
    bucket_gather<NHID1, 1><<<NBUCK2, 256, 0, stream>>>(
        xsb, csc_tmp, gbase, ghist, dinv, b1, batch, h1b, N);

    // 8. GEMM2 (MFMA): hw2b = bf16((h1 @ W2) * dinv[row])  (into dead xsb region)
    gemm_mfma<NCLASS, NHID1, true><<<(N + 127) / 128, 256, 0, stream>>>(
        h1b, w2t, dinv, (unsigned short*)hw2b, N);

    // 9. gather layer 2 + fused global_add_pool
    hipMemsetAsync(pooled, 0, NUM_GRAPHS * NCLASS * sizeof(float), stream);
    bucket_gather<NCLASS, 2><<<NBUCK2, 256, 0, stream>>>(
        hw2b, csc_tmp, gbase, ghist, dinv, b2, batch, pooled, N);

    // 10. head
    head_kernel<<<1, 256, 0, stream>>>(pooled, l1w, l1b, l2w, l2b, out);
}

// Round 6
// 411.570 us; speedup vs baseline: 5.1124x; 5.1124x over previous
//
#include <hip/hip_runtime.h>
#include <hip/hip_bf16.h>
#include <math.h>

#define N_NODES 100000
#define N_EDGES 1600000
#define NFEAT 256
#define NHID1 128
#define NCLASS 64
#define NUM_GRAPHS 64

#define POOL_CHUNK 64

// bucket geometry: bucket = col >> 8 (256 nodes per bucket)
#define NBUCK 391                    // ceil(100000/256)
#define EPB 8192                     // edges per block in binning passes
#define NBLK_A 196                   // ceil(1600000/8192)

typedef __attribute__((ext_vector_type(8))) short bf16x8;
typedef __attribute__((ext_vector_type(4))) float f32x4;

// ---------------- bf16 helpers (bit-level, RNE) ----------------

__device__ __forceinline__ unsigned short f2bf(float f) {
    unsigned u = __float_as_uint(f);
    u += 0x7fffu + ((u >> 16) & 1u);   // round to nearest even
    return (unsigned short)(u >> 16);
}
__device__ __forceinline__ unsigned packbf2(float lo, float hi) {
    return (unsigned)f2bf(lo) | ((unsigned)f2bf(hi) << 16);
}
__device__ __forceinline__ float bflo(unsigned p) { return __uint_as_float(p << 16); }
__device__ __forceinline__ float bfhi(unsigned p) { return __uint_as_float(p & 0xffff0000u); }

// ---------------- pass A1: bucket histogram (block-aggregated atomics) ----------------

__global__ __launch_bounds__(256) void hist_kernel(const int* __restrict__ cols,
                                                   int* __restrict__ ghist, int nE) {
    __shared__ int h[NBUCK];
    const int tid = threadIdx.x;
    for (int i = tid; i < NBUCK; i += 256) h[i] = 0;
    __syncthreads();
    long base = (long)blockIdx.x * EPB;
    for (int j = tid; j < EPB; j += 256) {
        long idx = base + j;
        if (idx < nE) atomicAdd(&h[cols[idx] >> 8], 1);
    }
    __syncthreads();
    for (int i = tid; i < NBUCK; i += 256) {
        int v = h[i];
        if (v) atomicAdd(&ghist[i], v);
    }
}

// ---------------- bucket scan: 391 entries -> gbase, gcursor ----------------

__global__ __launch_bounds__(512) void bucket_scan_kernel(const int* __restrict__ ghist,
                                                          int* __restrict__ gbase,
                                                          int* __restrict__ gcursor) {
    __shared__ int sh[512];
    int t = threadIdx.x;
    int v = (t < NBUCK) ? ghist[t] : 0;
    sh[t] = v;
    __syncthreads();
    for (int off = 1; off < 512; off <<= 1) {
        int add = (t >= off) ? sh[t - off] : 0;
        __syncthreads();
        sh[t] += add;
        __syncthreads();
    }
    if (t < NBUCK) {
        int excl = sh[t] - v;
        gbase[t] = excl;
        gcursor[t] = excl;
    }
}

// ---------------- pass A2: scatter edges into bucket-grouped csc_tmp ----------------
// record: .x = r | ((col&255)<<17), .y = w bits

__global__ __launch_bounds__(256) void scatter_bucket_kernel(const int* __restrict__ rows,
                                                             const int* __restrict__ cols,
                                                             const float* __restrict__ w,
                                                             int* __restrict__ gcursor,
                                                             int2* __restrict__ csc_tmp, int nE) {
    __shared__ int h[NBUCK];
    __shared__ int bb[NBUCK];
    __shared__ unsigned short rk[EPB];
    const int tid = threadIdx.x;
    for (int i = tid; i < NBUCK; i += 256) h[i] = 0;
    __syncthreads();
    long base = (long)blockIdx.x * EPB;
    for (int j = tid; j < EPB; j += 256) {
        long idx = base + j;
        if (idx < nE) rk[j] = (unsigned short)atomicAdd(&h[cols[idx] >> 8], 1);
    }
    __syncthreads();
    for (int i = tid; i < NBUCK; i += 256) {
        int v = h[i];
        if (v) bb[i] = atomicAdd(&gcursor[i], v);
    }
    __syncthreads();
    for (int j = tid; j < EPB; j += 256) {
        long idx = base + j;
        if (idx < nE) {
            int c = cols[idx];
            int b = c >> 8;
            int pos = bb[b] + (int)rk[j];
            csc_tmp[pos] = make_int2((rows[idx] & 0x1FFFF) | ((c & 255) << 17),
                                     __float_as_int(w[idx]));
        }
    }
}

// ---------------- pass B: per-bucket node-level CSC + deg/dinv + starts/cnt ----------------

__global__ __launch_bounds__(256) void build_csc_kernel(const int2* __restrict__ csc_tmp,
                                                        const int* __restrict__ gbase,
                                                        const int* __restrict__ ghist,
                                                        int2* __restrict__ edges,
                                                        int* __restrict__ starts,
                                                        int* __restrict__ cnt,
                                                        float* __restrict__ dinv, int n) {
    __shared__ int ncnt[256];
    __shared__ float nws[256];
    __shared__ int sh[256];
    __shared__ int ncur[256];
    const int tid = threadIdx.x;
    const int b = blockIdx.x;
    const int base = gbase[b];
    const int cntb = ghist[b];

    ncnt[tid] = 0;
    nws[tid] = 0.f;
    __syncthreads();

    // sweep 1: per-node count + weight sum
    for (int i = tid; i < cntb; i += 256) {
        int2 rec = csc_tmp[base + i];
        int local = ((unsigned)rec.x) >> 17;
        atomicAdd(&ncnt[local], 1);
        atomicAdd(&nws[local], __int_as_float(rec.y));
    }
    __syncthreads();

    // exclusive scan over 256 node counts
    int v = ncnt[tid];
    sh[tid] = v;
    __syncthreads();
    for (int off = 1; off < 256; off <<= 1) {
        int add = (tid >= off) ? sh[tid - off] : 0;
        __syncthreads();
        sh[tid] += add;
        __syncthreads();
    }
    int excl = sh[tid] - v;
    ncur[tid] = excl;

    int node = (b << 8) + tid;
    if (node < n) {
        cnt[node] = v;
        starts[node] = base + excl;
        dinv[node] = rsqrtf(1.0f + nws[tid]);
    }
    __syncthreads();

    // sweep 2: place edges at exact node positions
    for (int i = tid; i < cntb; i += 256) {
        int2 rec = csc_tmp[base + i];
        int local = ((unsigned)rec.x) >> 17;
        int r = rec.x & 0x1FFFF;
        int pos = base + atomicAdd(&ncur[local], 1);
        edges[pos] = make_int2(r, rec.y);
    }
}

// ---------------- weight transpose + bf16 pack: W[K][Nn] f32 -> WT[Nn][K/2] dwords ----------------

__global__ void transpose_bf_kernel(const float* __restrict__ W, unsigned* __restrict__ WT,
                                    int K, int Nn) {
    int idx = blockIdx.x * blockDim.x + threadIdx.x;
    int total = Nn * (K / 2);
    if (idx < total) {
        int n = idx / (K / 2);
        int kp = idx - n * (K / 2);
        WT[idx] = packbf2(W[(2 * kp) * Nn + n], W[(2 * kp + 1) * Nn + n]);
    }
}

// ---------------- MFMA bf16 GEMM: C[M,NT] = A[M,KK] @ BT^T, epilogue *rowscale -> bf16 ----------------
// C-store is staged through LDS (unioned with the dead A/B staging buffers) so
// global writes are full coalesced dwordx4 rows instead of stride-16 u16 lanes.

template <int NT, int KK, bool ABF16>
__global__ __launch_bounds__(256) void gemm_mfma(const void* __restrict__ Av,
                                                 const unsigned* __restrict__ BT,
                                                 const float* __restrict__ rowscale,
                                                 unsigned short* __restrict__ C,
                                                 int M) {
    constexpr int CT = NT / 16;
    constexpr int KD = KK / 2;          // dwords per bf16 row
    constexpr int ASZ = 4 * 128 * 4 * 4;            // Al bytes
    constexpr int BSZ = 4 * NT * 4 * 4;             // Bl bytes
    constexpr int CPITCH = NT + 8;                  // u16 pitch (pad: bank rotation)
    constexpr int CSZ = 128 * CPITCH * 2;           // Cl bytes
    constexpr int SMEM = (ASZ + BSZ > CSZ) ? (ASZ + BSZ) : CSZ;
    __shared__ __align__(16) unsigned char smem[SMEM];
    unsigned (*Al)[128][4] = reinterpret_cast<unsigned (*)[128][4]>(smem);
    unsigned (*Bl)[NT][4]  = reinterpret_cast<unsigned (*)[NT][4]>(smem + ASZ);
    unsigned short* Cl     = reinterpret_cast<unsigned short*>(smem);

    const int tid = threadIdx.x;
    const int wave = tid >> 6;
    const int lane = tid & 63;
    const int quad = lane >> 4;
    const int l16 = lane & 15;
    const int row0 = blockIdx.x * 128;

    f32x4 acc[2][CT] = {};

    for (int k0 = 0; k0 < KK; k0 += 32) {
        // ---- stage A ----
        if (ABF16) {
            const unsigned* Ab = (const unsigned*)Av;
            #pragma unroll
            for (int i = 0; i < 2; i++) {
                int idx = tid + i * 256;
                int ar = idx >> 2, aq = idx & 3;
                uint4 v = make_uint4(0, 0, 0, 0);
                if (row0 + ar < M)
                    v = *(const uint4*)(Ab + (long)(row0 + ar) * KD + k0 / 2 + aq * 4);
                *(uint4*)&Al[aq][ar][0] = v;
            }
        } else {
            const float* Af = (const float*)Av;
            int ar = tid >> 1, ah = tid & 1;
            float4 v0 = make_float4(0, 0, 0, 0), v1 = v0, v2 = v0, v3 = v0;
            if (row0 + ar < M) {
                const float* p = Af + (long)(row0 + ar) * KK + k0 + ah * 16;
                v0 = *(const float4*)p;
                v1 = *(const float4*)(p + 4);
                v2 = *(const float4*)(p + 8);
                v3 = *(const float4*)(p + 12);
            }
            uint4 d0 = make_uint4(packbf2(v0.x, v0.y), packbf2(v0.z, v0.w),
                                  packbf2(v1.x, v1.y), packbf2(v1.z, v1.w));
            uint4 d1 = make_uint4(packbf2(v2.x, v2.y), packbf2(v2.z, v2.w),
                                  packbf2(v3.x, v3.y), packbf2(v3.z, v3.w));
            *(uint4*)&Al[ah * 2 + 0][ar][0] = d0;
            *(uint4*)&Al[ah * 2 + 1][ar][0] = d1;
        }
        // ---- stage B ----
        #pragma unroll
        for (int i = 0; i < NT / 64; i++) {
            int idx = tid + i * 256;
            int br = idx >> 2, bq = idx & 3;
            *(uint4*)&Bl[bq][br][0] = *(const uint4*)(BT + (long)br * KD + k0 / 2 + bq * 4);
        }
        __syncthreads();

        bf16x8 af[2];
        #pragma unroll
        for (int rt = 0; rt < 2; rt++)
            af[rt] = *(const bf16x8*)&Al[quad][wave * 32 + rt * 16 + l16][0];
        #pragma unroll
        for (int ct = 0; ct < CT; ct++) {
            bf16x8 bfr = *(const bf16x8*)&Bl[quad][ct * 16 + l16][0];
            acc[0][ct] = __builtin_amdgcn_mfma_f32_16x16x32_bf16(af[0], bfr, acc[0][ct], 0, 0, 0);
            acc[1][ct] = __builtin_amdgcn_mfma_f32_16x16x32_bf16(af[1], bfr, acc[1][ct], 0, 0, 0);
        }
        __syncthreads();
    }

    // epilogue stage 1: acc -> Cl (LDS), scaled + packed to bf16
    // C/D layout: col = lane&15, row = quad*4+reg
    #pragma unroll
    for (int rt = 0; rt < 2; rt++) {
        #pragma unroll
        for (int reg = 0; reg < 4; reg++) {
            int rl = wave * 32 + rt * 16 + quad * 4 + reg;
            int grow = row0 + rl;
            float sc = (grow < M) ? rowscale[grow] : 0.f;
            unsigned short* cp = Cl + rl * CPITCH + l16;
            #pragma unroll
            for (int ct = 0; ct < CT; ct++)
                cp[ct * 16] = f2bf(acc[rt][ct][reg] * sc);
        }
    }
    __syncthreads();

    // epilogue stage 2: coalesced dwordx4 row writes
    constexpr int RDW = NT / 2;                 // dwords per C row
    unsigned* Cg = (unsigned*)C;
    for (int i = tid * 4; i < 128 * RDW; i += 256 * 4) {
        int r = i / RDW;
        int c = i - r * RDW;                    // multiple of 4 (RDW % 4 == 0)
        int grow = row0 + r;
        if (grow < M) {
            uint4 v = *(const uint4*)(Cl + r * CPITCH + c * 2);
            *(uint4*)(Cg + (long)grow * RDW + c) = v;
        }
    }
}

// ---------------- gather-aggregate over bf16 features (4x unrolled for MLP) ----------------

template <int F, bool RELU, bool BF16OUT>
__global__ __launch_bounds__(256) void gather_agg_bf(const unsigned* __restrict__ xsb,
                                                     const int2* __restrict__ edges,
                                                     const int* __restrict__ starts,
                                                     const int* __restrict__ cnt,
                                                     const float* __restrict__ dinv,
                                                     const float* __restrict__ bias,
                                                     void* __restrict__ outv, int n) {
    constexpr int G = F / 8;        // lanes per node; each lane covers 8 features
    constexpr int FU = F / 2;       // uints per row
    int gt = blockIdx.x * blockDim.x + threadIdx.x;
    int node = gt / G;
    int lane = gt - node * G;
    if (node >= n) return;

    int s = starts[node];
    int c = cnt[node];
    int e = s + c;
    float acc[8] = {};
    const unsigned* lbase = xsb + lane * 4;

    int j = s;
    // unroll 4: batch edge-record loads, then 4 independent gathers in flight
    for (; j + 3 < e; j += 4) {
        int2 e0 = edges[j];
        int2 e1 = edges[j + 1];
        int2 e2 = edges[j + 2];
        int2 e3 = edges[j + 3];
        uint4 p0 = *(const uint4*)(lbase + (long)e0.x * FU);
        uint4 p1 = *(const uint4*)(lbase + (long)e1.x * FU);
        uint4 p2 = *(const uint4*)(lbase + (long)e2.x * FU);
        uint4 p3 = *(const uint4*)(lbase + (long)e3.x * FU);
        float w0 = __int_as_float(e0.y);
        float w1 = __int_as_float(e1.y);
        float w2 = __int_as_float(e2.y);
        float w3 = __int_as_float(e3.y);
        acc[0] += bflo(p0.x) * w0; acc[1] += bfhi(p0.x) * w0;
        acc[2] += bflo(p0.y) * w0; acc[3] += bfhi(p0.y) * w0;
        acc[4] += bflo(p0.z) * w0; acc[5] += bfhi(p0.z) * w0;
        acc[6] += bflo(p0.w) * w0; acc[7] += bfhi(p0.w) * w0;
        acc[0] += bflo(p1.x) * w1; acc[1] += bfhi(p1.x) * w1;
        acc[2] += bflo(p1.y) * w1; acc[3] += bfhi(p1.y) * w1;
        acc[4] += bflo(p1.z) * w1; acc[5] += bfhi(p1.z) * w1;
        acc[6] += bflo(p1.w) * w1; acc[7] += bfhi(p1.w) * w1;
        acc[0] += bflo(p2.x) * w2; acc[1] += bfhi(p2.x) * w2;
        acc[2] += bflo(p2.y) * w2; acc[3] += bfhi(p2.y) * w2;
        acc[4] += bflo(p2.z) * w2; acc[5] += bfhi(p2.z) * w2;
        acc[6] += bflo(p2.w) * w2; acc[7] += bfhi(p2.w) * w2;
        acc[0] += bflo(p3.x) * w3; acc[1] += bfhi(p3.x) * w3;
        acc[2] += bflo(p3.y) * w3; acc[3] += bfhi(p3.y) * w3;
        acc[4] += bflo(p3.z) * w3; acc[5] += bfhi(p3.z) * w3;
        acc[6] += bflo(p3.w) * w3; acc[7] += bfhi(p3.w) * w3;
    }
    for (; j < e; j++) {
        int2 ed = edges[j];
        float wv = __int_as_float(ed.y);
        uint4 p = *(const uint4*)(lbase + (long)ed.x * FU);
        acc[0] += bflo(p.x) * wv; acc[1] += bfhi(p.x) * wv;
        acc[2] += bflo(p.y) * wv; acc[3] += bfhi(p.y) * wv;
        acc[4] += bflo(p.z) * wv; acc[5] += bfhi(p.z) * wv;
        acc[6] += bflo(p.w) * wv; acc[7] += bfhi(p.w) * wv;
    }

    float d = dinv[node];
    uint4 sp = *(const uint4*)(lbase + (long)node * FU);
    float sv[8] = { bflo(sp.x), bfhi(sp.x), bflo(sp.y), bfhi(sp.y),
                    bflo(sp.z), bfhi(sp.z), bflo(sp.w), bfhi(sp.w) };
    float4 bb0 = ((const float4*)bias)[lane * 2];
    float4 bb1 = ((const float4*)bias)[lane * 2 + 1];
    float bbv[8] = { bb0.x, bb0.y, bb0.z, bb0.w, bb1.x, bb1.y, bb1.z, bb1.w };
    float r[8];
    #pragma unroll
    for (int i = 0; i < 8; i++) {
        float v = d * (acc[i] + sv[i]) + bbv[i];
        r[i] = RELU ? fmaxf(v, 0.f) : v;
    }
    if (BF16OUT) {
        unsigned* ob = (unsigned*)outv;
        uint4 pk = make_uint4(packbf2(r[0], r[1]), packbf2(r[2], r[3]),
                              packbf2(r[4], r[5]), packbf2(r[6], r[7]));
        *(uint4*)(ob + (long)node * FU + lane * 4) = pk;
    } else {
        float* o = (float*)outv + (long)node * F + lane * 8;
        *(float4*)o       = make_float4(r[0], r[1], r[2], r[3]);
        *(float4*)(o + 4) = make_float4(r[4], r[5], r[6], r[7]);
    }
}

// ---------------- pooling over sorted batch ----------------

__global__ void pool_kernel(const float* __restrict__ h,
                            const int* __restrict__ batch,
                            float* __restrict__ pooled,
                            int n) {
    int f = threadIdx.x;  // 0..63
    long start = (long)blockIdx.x * POOL_CHUNK;
    long end = start + POOL_CHUNK;
    if (end > n) end = n;
    if (start >= end) return;
    int cur = batch[start];
    float acc = 0.f;
    for (long i = start; i < end; i++) {
        int g = batch[i];
        if (g != cur) {
            atomicAdd(&pooled[cur * NCLASS + f], acc);
            acc = 0.f;
            cur = g;
        }
        acc += h[i * NCLASS + f];
    }
    atomicAdd(&pooled[cur * NCLASS + f], acc);
}

// ---------------- head: 256 threads, all-LDS MLP + log_softmax + argmax ----------------

__global__ __launch_bounds__(256) void head_kernel(const float* __restrict__ pooled,
                                                   const float* __restrict__ l1w,
                                                   const float* __restrict__ l1b,
                                                   const float* __restrict__ l2w,
                                                   const float* __restrict__ l2b,
                                                   float* __restrict__ out) {
    __shared__ float P[64][68];
    __shared__ float W[64][68];
    __shared__ float red0[64][4];
    __shared__ float red1[64][4];
    const int tid = threadIdx.x;

    for (int i = tid; i < 1024; i += 256) {
        int r = i >> 4;
        int cq = (i & 15) * 4;
        *(float4*)&P[r][cq] = *(const float4*)&pooled[r * 64 + cq];
        *(float4*)&W[r][cq] = *(const float4*)&l1w[r * 64 + cq];
    }
    __syncthreads();

    const int g = tid >> 2;
    const int q = tid & 3;
    const int j0 = q * 16;

    float hacc[16];
    #pragma unroll
    for (int jj = 0; jj < 16; jj++) hacc[jj] = l1b[j0 + jj];

    for (int c = 0; c < 64; c++) {
        float pv = P[g][c];
        #pragma unroll
        for (int jj = 0; jj < 16; jj += 4) {
            float4 wv = *(const float4*)&W[c][j0 + jj];
            hacc[jj + 0] += pv * wv.x;
            hacc[jj + 1] += pv * wv.y;
            hacc[jj + 2] += pv * wv.z;
            hacc[jj + 3] += pv * wv.w;
        }
    }

    float o0 = 0.f, o1 = 0.f;
    #pragma unroll
    for (int jj = 0; jj < 16; jj++) {
        float h = fmaxf(hacc[jj], 0.f);
        o0 += h * l2w[(j0 + jj) * 2];
        o1 += h * l2w[(j0 + jj) * 2 + 1];
    }
    red0[g][q] = o0;
    red1[g][q] = o1;
    __syncthreads();

    if (q == 0) {
        float a0 = red0[g][0] + red0[g][1] + red0[g][2] + red0[g][3] + l2b[0];
        float a1 = red1[g][0] + red1[g][1] + red1[g][2] + red1[g][3] + l2b[1];
        float m = fmaxf(a0, a1);
        float lse = m + logf(expf(a0 - m) + expf(a1 - m));
        out[g * 2 + 0] = a0 - lse;
        out[g * 2 + 1] = a1 - lse;
        out[128 + g] = (a1 > a0) ? 1.f : 0.f;
        out[192 + g * 2 + 0] = a0;
        out[192 + g * 2 + 1] = a1;
    }
}

// ---------------- launch ----------------

extern "C" void kernel_launch(void* const* d_in, const int* in_sizes, int n_in,
                              void* d_out, int out_size, void* d_ws, size_t ws_size,
                              hipStream_t stream) {
    const float* x   = (const float*)d_in[0];           // [N, 256]
    const int* eidx  = (const int*)d_in[1];             // [2, E] flat
    const float* ew  = (const float*)d_in[2];           // [E]
    const int* batch = (const int*)d_in[3];             // [N]
    const float* W1  = (const float*)d_in[4];           // [256,128]
    const float* b1  = (const float*)d_in[5];
    const float* W2  = (const float*)d_in[6];           // [128,64]
    const float* b2  = (const float*)d_in[7];
    const float* l1w = (const float*)d_in[8];           // [64,64]
    const float* l1b = (const float*)d_in[9];
    const float* l2w = (const float*)d_in[10];          // [64,2]
    const float* l2b = (const float*)d_in[11];
    float* out = (float*)d_out;

    const int N = N_NODES, E = N_EDGES;
    const int* rows = eidx;
    const int* cols = eidx + E;

    // workspace layout (float offsets; 16B alignment for vector arrays)
    float* ws = (float*)d_ws;
    int*   ghist   = (int*)ws;                  // 391   -> pad to 512
    int*   gbase   = ghist + 512;               // 391   -> pad to 512
    int*   gcursor = gbase + 512;               // 391   -> pad to 512
    float* dinv    = (float*)(gcursor + 512);   // N
    int*   cnt     = (int*)(dinv + N);          // N
    int*   starts  = cnt + N;                   // N
    unsigned* w1t  = (unsigned*)(starts + N);   // 16384
    unsigned* w2t  = w1t + 16384;               // 4096
    int2*  csc_tmp = (int2*)(w2t + 4096);       // E int2 (16B-aligned)
    int2*  edges   = csc_tmp + E;               // E int2
    unsigned* xsb  = (unsigned*)(edges + E);    // N*64 dw
    unsigned* h1b  = xsb + (long)N * 64;        // N*64 dw
    float* pooled  = (float*)(h1b + (long)N * 64);  // 4096
    unsigned* hw2b = xsb;                       // reuse dead xsb: N*32 dw
    float* h2 = (float*)h1b;                    // reuse dead h1b: N*64 f32

    // 1. bucket histogram (block-aggregated atomics)
    hipMemsetAsync(ghist, 0, 512 * sizeof(int), stream);
    hist_kernel<<<NBLK_A, 256, 0, stream>>>(cols, ghist, E);

    // 2. bucket scan
    bucket_scan_kernel<<<1, 512, 0, stream>>>(ghist, gbase, gcursor);

    // 3. scatter into bucket-grouped tmp
    scatter_bucket_kernel<<<NBLK_A, 256, 0, stream>>>(rows, cols, ew, gcursor, csc_tmp, E);

    // 4. per-bucket node-level CSC + deg/dinv/starts/cnt
    build_csc_kernel<<<NBUCK, 256, 0, stream>>>(csc_tmp, gbase, ghist, edges, starts, cnt, dinv, N);

    // 5. weight prep
    transpose_bf_kernel<<<64, 256, 0, stream>>>(W1, w1t, NFEAT, NHID1);
    transpose_bf_kernel<<<16, 256, 0, stream>>>(W2, w2t, NHID1, NCLASS);

    // 6. GEMM1 (MFMA): xsb = bf16((x @ W1) * dinv[row])
    gemm_mfma<NHID1, NFEAT, false><<<(N + 127) / 128, 256, 0, stream>>>(
        x, w1t, dinv, (unsigned short*)xsb, N);

    // 7. gather layer 1: h1b = bf16(relu(dinv[c]*(agg + self) + b1))
    {
        long threads = (long)N * (NHID1 / 8);
        gather_agg_bf<NHID1, true, true><<<(threads + 255) / 256, 256, 0, stream>>>(
            xsb, edges, starts, cnt, dinv, b1, h1b, N);
    }

    // 8. GEMM2 (MFMA): hw2b = bf16((h1 @ W2) * dinv[row])  (into dead xsb region)
    gemm_mfma<NCLASS, NHID1, true><<<(N + 127) / 128, 256, 0, stream>>>(
        h1b, w2t, dinv, (unsigned short*)hw2b, N);

    // 9. gather layer 2: h2 = f32 relu(dinv[c]*(agg + self) + b2)  (into dead h1b region)
    {
        long threads = (long)N * (NCLASS / 8);
        gather_agg_bf<NCLASS, true, false><<<(threads + 255) / 256, 256, 0, stream>>>(
            hw2b, edges, starts, cnt, dinv, b2, h2, N);
    }

    // 10. pool
    hipMemsetAsync(pooled, 0, NUM_GRAPHS * NCLASS * sizeof(float), stream);
    {
        int blocks = (N + POOL_CHUNK - 1) / POOL_CHUNK;
        pool_kernel<<<blocks, 64, 0, stream>>>(h2, batch, pooled, N);
    }

    // 11. head
    head_kernel<<<1, 256, 0, stream>>>(pooled, l1w, l1b, l2w, l2b, out);
}